// Round 6
// baseline (266.442 us; speedup 1.0000x reference)
//
#include <hip/hip_runtime.h>
#include <hip/hip_fp16.h>

#define NN 50000
#define NE 600000
#define NG 3
#define D  128
#define NI 4096
#define BW 1024                         // nodes per bucket
#define NBUCK 49                        // ceil(NN/BW)
#define CAP 16384                       // slots per bucket (mean fill 12.3K, sigma~110)
#define REGION (NBUCK * CAP)            // 802816 slots per graph (< 2^20: rp32 packable)
#define EPT_BIN 16
#define EPB_BIN (256 * EPT_BIN)         // 4096 edges per block
#define NBLK_BIN ((NE + EPB_BIN - 1) / EPB_BIN)   // 147
#define XCVT_BLKS 3125                  // NN*D/8 threads, 8 floats each
#define WCVT_BLKS 48

typedef _Float16 half8 __attribute__((ext_vector_type(8)));
typedef float floatx4 __attribute__((ext_vector_type(4)));

static __device__ __forceinline__ float wextract(unsigned int v) {
  unsigned short u = (unsigned short)(v >> 16);
  _Float16 h;
  __builtin_memcpy(&h, &u, 2);
  return (float)h;
}

static __device__ __forceinline__ unsigned short h16(float f) {
  _Float16 h = (_Float16)f;
  unsigned short u;
  __builtin_memcpy(&u, &h, 2);
  return u;
}

// ---------------- fused prep: xcvt + wcvt + cursor init ----------------
// R14: count pass + bscan ELIMINATED. Buckets are oversized (CAP=16384 slots);
// bin_kernel self-allocates per-(block,bucket) chunks from gcur cursors, which
// are initialized here (one tiny branch block). No memset dispatch needed.
// R12 LESSON: never scatter 4B stores to final per-node CSR slots from an
// unsorted stream (17x write amplification) — bucket presort gives locality.
// R13 LESSON: never do per-edge random GLOBAL atomics (68MB write traffic for a
// 1.8MB table; cross-XCD line bouncing). LDS histogram + per-bucket atomics only.

__global__ __launch_bounds__(256) void prep_kernel(
    const float* __restrict__ x, __half* __restrict__ xh,
    const float* __restrict__ W0, const float* __restrict__ W1, const float* __restrict__ W2,
    const float* __restrict__ W3, const float* __restrict__ W4, const float* __restrict__ W5,
    __half* __restrict__ Wf, int* __restrict__ gcur) {
  int blk = blockIdx.x;
  int tid = threadIdx.x;
  if (blk < XCVT_BLKS) {
    int i = blk * 256 + tid;
    size_t base = (size_t)i * 8;
    float4 v0 = *(const float4*)&x[base];
    float4 v1 = *(const float4*)&x[base + 4];
    half8 h;
    h[0] = (_Float16)v0.x; h[1] = (_Float16)v0.y; h[2] = (_Float16)v0.z; h[3] = (_Float16)v0.w;
    h[4] = (_Float16)v1.x; h[5] = (_Float16)v1.y; h[6] = (_Float16)v1.z; h[7] = (_Float16)v1.w;
    *(half8*)&xh[base] = h;
  } else if (blk < XCVT_BLKS + WCVT_BLKS) {
    const float* Wm[6] = {W0, W1, W2, W3, W4, W5};
    int t = (blk - XCVT_BLKS) * 256 + tid;     // 0 .. 6*2048-1
    int mat = t >> 11;
    int fr = (t >> 6) & 31;
    int lane = t & 63;
    int tt = fr >> 2, ks = fr & 3;
    int n = tt * 16 + (lane & 15);
    int kb = ks * 32 + (lane >> 4) * 8;
    const float* W = Wm[mat];
#pragma unroll
    for (int j = 0; j < 8; j++)
      Wf[(size_t)t * 8 + j] = __float2half(W[(kb + j) * 128 + n]);
  } else {
    // cursor init: gcur[g*NBUCK+b] = b*CAP (completes before bin_kernel launches)
    if (tid < NG * NBUCK) gcur[tid] = (tid % NBUCK) * CAP;
  }
}

// per-wave LDS histograms (cuts same-address LDS atomic serialization 4x), then
// per-(block,bucket) contiguous chunk allocation straight from global cursors.
__global__ __launch_bounds__(256) void bin_kernel(const int* __restrict__ e0,
    const int* __restrict__ e1, const int* __restrict__ e2,
    int* __restrict__ gcur, unsigned int* __restrict__ binned) {
  __shared__ int cnt[4][NBUCK];
  __shared__ int base[NBUCK];
  __shared__ int woff[4][NBUCK];
  int g = blockIdx.y;
  const int* ei = (g == 0) ? e0 : ((g == 1) ? e1 : e2);
  int tid = threadIdx.x;
  int wave = tid >> 6;
  if (tid < NBUCK) { cnt[0][tid] = 0; cnt[1][tid] = 0; cnt[2][tid] = 0; cnt[3][tid] = 0; }
  __syncthreads();
  int estart = blockIdx.x * EPB_BIN;
  int src[EPT_BIN], dst[EPT_BIN], rk[EPT_BIN];
#pragma unroll
  for (int i = 0; i < EPT_BIN; i++) {
    int e = estart + tid + i * 256;
    if (e < NE) {
      src[i] = ei[e];
      dst[i] = ei[NE + e];
      rk[i] = atomicAdd(&cnt[wave][dst[i] >> 10], 1);
    } else {
      rk[i] = -1;
    }
  }
  __syncthreads();
  if (tid < NBUCK) {
    int c0 = cnt[0][tid], c1 = cnt[1][tid], c2 = cnt[2][tid], c3 = cnt[3][tid];
    int total = c0 + c1 + c2 + c3;
    base[tid] = (total > 0) ? atomicAdd(&gcur[g * NBUCK + tid], total) : 0;
    woff[0][tid] = 0; woff[1][tid] = c0; woff[2][tid] = c0 + c1; woff[3][tid] = c0 + c1 + c2;
  }
  __syncthreads();
#pragma unroll
  for (int i = 0; i < EPT_BIN; i++) {
    if (rk[i] >= 0) {
      int b = dst[i] >> 10;
      int pos = base[b] + woff[wave][b] + rk[i];
      if (pos < (b + 1) * CAP)   // overflow guard (never fires at CAP=16K, mean 12.3K)
        binned[(size_t)g * REGION + pos] =
            (unsigned int)src[i] | ((unsigned int)dst[i] << 16);
    }
  }
}

// csr: per-bucket degree histogram from binned -> packed rp32 (start | deg<<20),
// dinv fp32 (for aggb) and dinvh fp16 (for fillp's gather).
__global__ __launch_bounds__(256) void csr_kernel(const unsigned int* __restrict__ binned,
    const int* __restrict__ gcur, unsigned int* __restrict__ rp32,
    float* __restrict__ dinv, unsigned short* __restrict__ dinvh) {
  __shared__ int deg[BW];
  __shared__ int wsum[4];
  int g = blockIdx.y, b = blockIdx.x;
  int tid = threadIdx.x;
  int node0 = b * BW;
  int cbase = b * CAP;
  int total = min(gcur[g * NBUCK + b] - cbase, CAP);
  const unsigned int* bp = binned + (size_t)g * REGION + cbase;
  for (int i = tid; i < BW; i += 256) deg[i] = 0;
  __syncthreads();
  for (int e = tid; e < total; e += 256) {
    unsigned int p = bp[e];
    atomicAdd(&deg[(int)(p >> 16) - node0], 1);
  }
  __syncthreads();
  int d0 = deg[tid * 4], d1 = deg[tid * 4 + 1], d2 = deg[tid * 4 + 2], d3 = deg[tid * 4 + 3];
  int s = d0 + d1 + d2 + d3;
  int lane = tid & 63;
  int incl = s;
#pragma unroll
  for (int off = 1; off < 64; off <<= 1) {
    int n = __shfl_up(incl, off, 64);
    if (lane >= off) incl += n;
  }
  if (lane == 63) wsum[tid >> 6] = incl;
  __syncthreads();
  int wbase = 0;
#pragma unroll
  for (int w = 0; w < 4; w++)
    if (w < (tid >> 6)) wbase += wsum[w];
  int ex = wbase + incl - s;
  int exs[4] = {ex, ex + d0, ex + d0 + d1, ex + d0 + d1 + d2};
  int ds[4] = {d0, d1, d2, d3};
#pragma unroll
  for (int k = 0; k < 4; k++) {
    int node = node0 + tid * 4 + k;
    if (node < NN) {
      unsigned int st = (unsigned int)(cbase + exs[k]);
      rp32[g * NN + node] = st | ((unsigned int)ds[k] << 20);
      float di = rsqrtf((float)ds[k] + 1.0f);   // deg incl. self loop
      dinv[g * NN + node] = di;
      dinvh[g * NN + node] = h16(di);
    }
  }
}

// fillp: scatter packed (src | fp16 dinv[src]) into bucket-local colp slots.
// Writes stay within this bucket's 64KB window -> full line utilization.
__global__ __launch_bounds__(256) void fillp_kernel(const unsigned int* __restrict__ binned,
    const int* __restrict__ gcur, const unsigned int* __restrict__ rp32,
    const unsigned short* __restrict__ dinvh, unsigned int* __restrict__ colp) {
  __shared__ int cur[BW];
  int g = blockIdx.y, b = blockIdx.x;
  int tid = threadIdx.x;
  int node0 = b * BW;
  int cbase = b * CAP;
  int total = min(gcur[g * NBUCK + b] - cbase, CAP);
  const unsigned int* bp = binned + (size_t)g * REGION + cbase;
  for (int i = tid; i < BW; i += 256) {
    int node = node0 + i;
    cur[i] = (node < NN) ? (int)(rp32[g * NN + node] & 0xFFFFFu) : 0;
  }
  __syncthreads();
  const unsigned short* dh = dinvh + (size_t)g * NN;
  unsigned int* cg = colp + (size_t)g * REGION;
  for (int e = tid; e < total; e += 256) {
    unsigned int p = bp[e];
    int srcid = (int)(p & 0xffffu);
    int r = atomicAdd(&cur[(int)(p >> 16) - node0], 1);
    cg[r] = (unsigned int)srcid | ((unsigned int)dh[srcid] << 16);
  }
}

// ---------------- aggregation: one wave per 4 (node, branch) rows ----------------
// blockIdx.y = branch. 4 node-groups x 16 lanes; lane l16 owns features
// l16*8 .. l16*8+7 of its group's node (full 128-feature row per 16-lane group).
// Amortizes the per-node prologue 4x, loads the self row once, and needs no
// cross-lane reduction. R15: (1) colp reads + t1 stores are NONTEMPORAL — these
// are read-once/write-once streams; keeping them out of L2 protects the random
// xh gather working set (12.8MB vs 4MB per-XCD L2). (2) inner edge batch 4->8:
// 8 independent 16B gathers in flight per lane (accumulation order unchanged ->
// bitwise-identical output). VGPR ~60, below the 64 occupancy step.

__global__ __launch_bounds__(256) void aggb_kernel(
    const __half* __restrict__ srch, const unsigned int* __restrict__ rp32,
    const unsigned int* __restrict__ colp, const float* __restrict__ dinv,
    const int* __restrict__ index, __half* __restrict__ tout, int nrows) {
  int b = blockIdx.y;
  int lane = threadIdx.x & 63;
  int grp = lane >> 4;            // node-group within wave
  int l16 = lane & 15;            // feature slot: features l16*8 .. +7
  int gb = grp << 4;              // group's lane base for shfl broadcast
  int wv = (blockIdx.x * 256 + threadIdx.x) >> 6;   // global wave id
  int w = wv * 4 + grp;           // output row this group owns
  int valid = (w < nrows);
  int wc = valid ? w : 0;
  int node = index ? index[wc] : wc;
  const _Float16* srcv = (const _Float16*)srch;
  unsigned int r32 = rp32[(size_t)b * NN + node];
  int s = (int)(r32 & 0xFFFFFu);
  int n = valid ? (int)(r32 >> 20) : 0;
  float di = dinv[b * NN + node];
  half8 selfh = *(const half8*)&srcv[(size_t)node * D + l16 * 8];
  float a[8];
#pragma unroll
  for (int k = 0; k < 8; k++) a[k] = di * (float)selfh[k];
  // wave-max degree across the 4 groups (uniform loop bound -> no divergence)
  int nmax = n;
  nmax = max(nmax, __shfl_xor(nmax, 16, 64));
  nmax = max(nmax, __shfl_xor(nmax, 32, 64));
  const unsigned int* cp = colp + (size_t)b * REGION;
  for (int j0 = 0; j0 < nmax; j0 += 16) {
    // each group loads up to 16 of its packed cols (64B coalesced per group)
    unsigned int c = (j0 + l16 < n) ? __builtin_nontemporal_load(&cp[s + j0 + l16]) : 0u;
    int rem = nmax - j0;
    rem = (rem > 16) ? 16 : rem;
    for (int jj = 0; jj < rem; jj += 8) {
      unsigned int v[8];
      half8 h[8];
#pragma unroll
      for (int u = 0; u < 8; u++) {
        v[u] = (unsigned int)__shfl((int)c, gb + jj + u, 64);
        h[u] = *(const half8*)&srcv[(size_t)(v[u] & 0xffffu) * D + l16 * 8];
      }
#pragma unroll
      for (int u = 0; u < 8; u++) {
        float wg = wextract(v[u]);
#pragma unroll
        for (int k = 0; k < 8; k++) a[k] = fmaf((float)h[u][k], wg, a[k]);
      }
    }
  }
  if (valid) {
    half8 o;
#pragma unroll
    for (int k = 0; k < 8; k++) o[k] = (_Float16)(di * a[k]);
    _Float16* tv = (_Float16*)tout;
    __builtin_nontemporal_store(o,
        (half8*)&tv[(size_t)b * nrows * D + (size_t)w * D + l16 * 8]);
  }
}

// ---------------- fused 3-branch MFMA fp16 matmul + bias + relu + max ----------------
// A staged through LDS (coalesced global half8 loads, padded stride 136).

#define ALD 136   // padded LDS row stride (halves); 272B, 16B-aligned, conflict-light

__global__ __launch_bounds__(256) void mmf_kernel(const __half* __restrict__ A,
    const __half* __restrict__ Wf,
    const float* __restrict__ B0, const float* __restrict__ B1, const float* __restrict__ B2,
    __half* __restrict__ outh, float* __restrict__ outf, int M) {
  __shared__ _Float16 As[128 * ALD];  // 34.8 KB
  __shared__ _Float16 Ws[16384];      // 32 KB
  const float* Bb[3] = {B0, B1, B2};
  const int tid = threadIdx.x;
  const int wave = tid >> 6, lane = tid & 63;
  const int wr = (wave >> 1) * 64, wc = (wave & 1) * 64;
  const int ln = lane & 15, quad = lane >> 4;
  const int row0 = blockIdx.x * 128;
  float om[4][4][4];

  for (int b = 0; b < 3; b++) {
    const __half* Wb = Wf + (size_t)b * 16384;
#pragma unroll
    for (int i = 0; i < 8; i++) {
      int id = tid + i * 256;
      *(half8*)&Ws[id * 8] = *(const half8*)&Wb[(size_t)id * 8];
    }
    const __half* Ab = A + (size_t)b * M * D;
#pragma unroll
    for (int i = 0; i < 8; i++) {
      int idx = tid + i * 256;          // 0..2047 half8 slots
      int r = idx >> 4, c8 = idx & 15;
      int gr = row0 + r;
      gr = (gr < M) ? gr : (M - 1);
      half8 v = *(const half8*)&Ab[(size_t)gr * D + c8 * 8];
      *(half8*)&As[r * ALD + c8 * 8] = v;
    }
    __syncthreads();

    float bias[4];
#pragma unroll
    for (int ct = 0; ct < 4; ct++) bias[ct] = Bb[b][wc + ct * 16 + ln];
    floatx4 acc[4][4];
#pragma unroll
    for (int rt = 0; rt < 4; rt++)
#pragma unroll
      for (int ct = 0; ct < 4; ct++)
        acc[rt][ct] = (floatx4){bias[ct], bias[ct], bias[ct], bias[ct]};

#pragma unroll
    for (int ks = 0; ks < 4; ks++) {
      half8 av[4];
#pragma unroll
      for (int rt = 0; rt < 4; rt++)
        av[rt] = *(const half8*)&As[(wr + rt * 16 + ln) * ALD + ks * 32 + quad * 8];
#pragma unroll
      for (int ct = 0; ct < 4; ct++) {
        int tt = (wc >> 4) + ct;
        half8 bv = *(const half8*)&Ws[((tt * 4 + ks) * 64 + lane) * 8];
#pragma unroll
        for (int rt = 0; rt < 4; rt++)
          acc[rt][ct] = __builtin_amdgcn_mfma_f32_16x16x32_f16(av[rt], bv, acc[rt][ct], 0, 0, 0);
      }
    }
#pragma unroll
    for (int rt = 0; rt < 4; rt++)
#pragma unroll
      for (int ct = 0; ct < 4; ct++)
#pragma unroll
        for (int r = 0; r < 4; r++) {
          float v = fmaxf(acc[rt][ct][r], 0.f);
          om[rt][ct][r] = (b == 0) ? v : fmaxf(om[rt][ct][r], v);
        }
    __syncthreads();
  }
#pragma unroll
  for (int rt = 0; rt < 4; rt++) {
    int m = row0 + wr + rt * 16 + quad * 4;
#pragma unroll
    for (int r = 0; r < 4; r++) {
      if (m + r < M) {
#pragma unroll
        for (int ct = 0; ct < 4; ct++) {
          int n = wc + ct * 16 + ln;
          if (outh) outh[(size_t)(m + r) * D + n] = __float2half(om[rt][ct][r]);
          else      outf[(size_t)(m + r) * D + n] = om[rt][ct][r];
        }
      }
    }
  }
}

// ---------------- launch ----------------

extern "C" void kernel_launch(void* const* d_in, const int* in_sizes, int n_in,
                              void* d_out, int out_size, void* d_ws, size_t ws_size,
                              hipStream_t stream) {
  const float* x = (const float*)d_in[0];
  const int* e0 = (const int*)d_in[1];
  const int* e1 = (const int*)d_in[2];
  const int* e2 = (const int*)d_in[3];
  const int* index = (const int*)d_in[4];
  const float* w1[3] = {(const float*)d_in[5], (const float*)d_in[9],  (const float*)d_in[13]};
  const float* b1[3] = {(const float*)d_in[6], (const float*)d_in[10], (const float*)d_in[14]};
  const float* w2[3] = {(const float*)d_in[7], (const float*)d_in[11], (const float*)d_in[15]};
  const float* b2[3] = {(const float*)d_in[8], (const float*)d_in[12], (const float*)d_in[16]};
  float* out = (float*)d_out;

  char* ws = (char*)d_ws;
  size_t o = 0;
  auto alloc = [&](size_t bytes) {
    o = (o + 255) & ~(size_t)255;
    void* p = ws + o;
    o += bytes;
    return p;
  };
  unsigned int* rp32 = (unsigned int*)alloc((size_t)NG * NN * 4);
  unsigned int* colp = (unsigned int*)alloc((size_t)NG * REGION * 4);   // 9.6 MB
  float*  dinv   = (float*)alloc((size_t)NG * NN * 4);
  unsigned short* dinvh = (unsigned short*)alloc((size_t)NG * NN * 2);
  int*    gcur   = (int*)alloc((size_t)NG * NBUCK * 4);
  __half* xh     = (__half*)alloc((size_t)NN * D * 2);        // 12.8 MB
  __half* Wf     = (__half*)alloc((size_t)6 * 128 * 128 * 2); // 196 KB
  __half* t1     = (__half*)alloc((size_t)NG * NN * D * 2);   // 38.4 MB
  __half* hacc   = (__half*)alloc((size_t)NN * D * 2);        // 12.8 MB
  unsigned int* binned = (unsigned int*)t1;  // alias: consumed by csr/fillp before aggb writes t1
  __half* t2     = t1;                       // alias: t1 free during layer 2
  (void)ws_size; (void)in_sizes; (void)n_in; (void)out_size;

  prep_kernel<<<XCVT_BLKS + WCVT_BLKS + 1, 256, 0, stream>>>(
      x, xh, w1[0], w1[1], w1[2], w2[0], w2[1], w2[2], Wf, gcur);
  bin_kernel<<<dim3(NBLK_BIN, NG), 256, 0, stream>>>(e0, e1, e2, gcur, binned);
  csr_kernel<<<dim3(NBUCK, NG), 256, 0, stream>>>(binned, gcur, rp32, dinv, dinvh);
  fillp_kernel<<<dim3(NBUCK, NG), 256, 0, stream>>>(binned, gcur, rp32, dinvh, colp);

  // layer 1: t1_b = Norm_b(xh);  hacc = max_b relu(t1_b @ W1_b + b1_b)   [fp16]
  aggb_kernel<<<dim3((NN + 15) / 16, NG), 256, 0, stream>>>(
      xh, rp32, colp, dinv, nullptr, t1, NN);
  mmf_kernel<<<(NN + 127) / 128, 256, 0, stream>>>(t1, Wf, b1[0], b1[1], b1[2],
                                                   hacc, nullptr, NN);
  // layer 2: t2_b = Norm_b(hacc)[index];  out = max_b relu(t2_b @ W2_b + b2_b)
  aggb_kernel<<<dim3((NI + 15) / 16, NG), 256, 0, stream>>>(
      hacc, rp32, colp, dinv, index, t2, NI);
  mmf_kernel<<<(NI + 127) / 128, 256, 0, stream>>>(t2, Wf + (size_t)3 * 16384,
                                                   b2[0], b2[1], b2[2], nullptr, out, NI);
}

// Round 7
// 265.740 us; speedup vs baseline: 1.0026x; 1.0026x over previous
//
#include <hip/hip_runtime.h>
#include <hip/hip_fp16.h>

#define NN 50000
#define NE 600000
#define NG 3
#define D  128
#define NI 4096
#define BW 1024                         // nodes per bucket
#define NBUCK 49                        // ceil(NN/BW)
#define CAP 16384                       // slots per bucket (mean fill 12.3K, sigma~110)
#define REGION (NBUCK * CAP)            // 802816 slots per graph (< 2^20: rp32 packable)
#define EPT_BIN 16
#define EPB_BIN (256 * EPT_BIN)         // 4096 edges per block
#define NBLK_BIN ((NE + EPB_BIN - 1) / EPB_BIN)   // 147
#define XCVT_BLKS 3125                  // NN*D/8 threads, 8 floats each
#define WCVT_BLKS 48

typedef _Float16 half8 __attribute__((ext_vector_type(8)));
typedef float floatx4 __attribute__((ext_vector_type(4)));

static __device__ __forceinline__ float wextract(unsigned int v) {
  unsigned short u = (unsigned short)(v >> 16);
  _Float16 h;
  __builtin_memcpy(&h, &u, 2);
  return (float)h;
}

static __device__ __forceinline__ unsigned short h16(float f) {
  _Float16 h = (_Float16)f;
  unsigned short u;
  __builtin_memcpy(&u, &h, 2);
  return u;
}

// ---------------- fused prep: xcvt + wcvt + cursor init ----------------
// R14: count pass + bscan ELIMINATED via oversized buckets (CAP=16384);
// bin_kernel self-allocates per-(block,bucket) chunks from gcur cursors.
// R12 LESSON: never scatter 4B stores to final per-node CSR slots from an
// unsorted stream (17x write amplification) — bucket presort gives locality.
// R13 LESSON: never do per-edge random GLOBAL atomics (68MB write traffic for a
// 1.8MB table; cross-XCD line bouncing). LDS histogram + per-bucket atomics only.
// R15 LESSON: aggb is THROUGHPUT-bound (occ 65->33% at same speed), not
// latency-bound; NT stores on a buffer the next kernel reads cost more than
// the L2 protection buys.

__global__ __launch_bounds__(256) void prep_kernel(
    const float* __restrict__ x, __half* __restrict__ xh,
    const float* __restrict__ W0, const float* __restrict__ W1, const float* __restrict__ W2,
    const float* __restrict__ W3, const float* __restrict__ W4, const float* __restrict__ W5,
    __half* __restrict__ Wf, int* __restrict__ gcur) {
  int blk = blockIdx.x;
  int tid = threadIdx.x;
  if (blk < XCVT_BLKS) {
    int i = blk * 256 + tid;
    size_t base = (size_t)i * 8;
    float4 v0 = *(const float4*)&x[base];
    float4 v1 = *(const float4*)&x[base + 4];
    half8 h;
    h[0] = (_Float16)v0.x; h[1] = (_Float16)v0.y; h[2] = (_Float16)v0.z; h[3] = (_Float16)v0.w;
    h[4] = (_Float16)v1.x; h[5] = (_Float16)v1.y; h[6] = (_Float16)v1.z; h[7] = (_Float16)v1.w;
    *(half8*)&xh[base] = h;
  } else if (blk < XCVT_BLKS + WCVT_BLKS) {
    const float* Wm[6] = {W0, W1, W2, W3, W4, W5};
    int t = (blk - XCVT_BLKS) * 256 + tid;     // 0 .. 6*2048-1
    int mat = t >> 11;
    int fr = (t >> 6) & 31;
    int lane = t & 63;
    int tt = fr >> 2, ks = fr & 3;
    int n = tt * 16 + (lane & 15);
    int kb = ks * 32 + (lane >> 4) * 8;
    const float* W = Wm[mat];
#pragma unroll
    for (int j = 0; j < 8; j++)
      Wf[(size_t)t * 8 + j] = __float2half(W[(kb + j) * 128 + n]);
  } else {
    // cursor init: gcur[g*NBUCK+b] = b*CAP (completes before bin_kernel launches)
    if (tid < NG * NBUCK) gcur[tid] = (tid % NBUCK) * CAP;
  }
}

// per-wave LDS histograms (cuts same-address LDS atomic serialization 4x), then
// per-(block,bucket) contiguous chunk allocation straight from global cursors.
__global__ __launch_bounds__(256) void bin_kernel(const int* __restrict__ e0,
    const int* __restrict__ e1, const int* __restrict__ e2,
    int* __restrict__ gcur, unsigned int* __restrict__ binned) {
  __shared__ int cnt[4][NBUCK];
  __shared__ int base[NBUCK];
  __shared__ int woff[4][NBUCK];
  int g = blockIdx.y;
  const int* ei = (g == 0) ? e0 : ((g == 1) ? e1 : e2);
  int tid = threadIdx.x;
  int wave = tid >> 6;
  if (tid < NBUCK) { cnt[0][tid] = 0; cnt[1][tid] = 0; cnt[2][tid] = 0; cnt[3][tid] = 0; }
  __syncthreads();
  int estart = blockIdx.x * EPB_BIN;
  int src[EPT_BIN], dst[EPT_BIN], rk[EPT_BIN];
#pragma unroll
  for (int i = 0; i < EPT_BIN; i++) {
    int e = estart + tid + i * 256;
    if (e < NE) {
      src[i] = ei[e];
      dst[i] = ei[NE + e];
      rk[i] = atomicAdd(&cnt[wave][dst[i] >> 10], 1);
    } else {
      rk[i] = -1;
    }
  }
  __syncthreads();
  if (tid < NBUCK) {
    int c0 = cnt[0][tid], c1 = cnt[1][tid], c2 = cnt[2][tid], c3 = cnt[3][tid];
    int total = c0 + c1 + c2 + c3;
    base[tid] = (total > 0) ? atomicAdd(&gcur[g * NBUCK + tid], total) : 0;
    woff[0][tid] = 0; woff[1][tid] = c0; woff[2][tid] = c0 + c1; woff[3][tid] = c0 + c1 + c2;
  }
  __syncthreads();
#pragma unroll
  for (int i = 0; i < EPT_BIN; i++) {
    if (rk[i] >= 0) {
      int b = dst[i] >> 10;
      int pos = base[b] + woff[wave][b] + rk[i];
      if (pos < (b + 1) * CAP)   // overflow guard (never fires at CAP=16K, mean 12.3K)
        binned[(size_t)g * REGION + pos] =
            (unsigned int)src[i] | ((unsigned int)dst[i] << 16);
    }
  }
}

// csr: per-bucket degree histogram from binned -> packed rp32 (start | deg<<20),
// dinv fp32 (for agg) and dinvh fp16 (for fillp's gather).
__global__ __launch_bounds__(256) void csr_kernel(const unsigned int* __restrict__ binned,
    const int* __restrict__ gcur, unsigned int* __restrict__ rp32,
    float* __restrict__ dinv, unsigned short* __restrict__ dinvh) {
  __shared__ int deg[BW];
  __shared__ int wsum[4];
  int g = blockIdx.y, b = blockIdx.x;
  int tid = threadIdx.x;
  int node0 = b * BW;
  int cbase = b * CAP;
  int total = min(gcur[g * NBUCK + b] - cbase, CAP);
  const unsigned int* bp = binned + (size_t)g * REGION + cbase;
  for (int i = tid; i < BW; i += 256) deg[i] = 0;
  __syncthreads();
  for (int e = tid; e < total; e += 256) {
    unsigned int p = bp[e];
    atomicAdd(&deg[(int)(p >> 16) - node0], 1);
  }
  __syncthreads();
  int d0 = deg[tid * 4], d1 = deg[tid * 4 + 1], d2 = deg[tid * 4 + 2], d3 = deg[tid * 4 + 3];
  int s = d0 + d1 + d2 + d3;
  int lane = tid & 63;
  int incl = s;
#pragma unroll
  for (int off = 1; off < 64; off <<= 1) {
    int n = __shfl_up(incl, off, 64);
    if (lane >= off) incl += n;
  }
  if (lane == 63) wsum[tid >> 6] = incl;
  __syncthreads();
  int wbase = 0;
#pragma unroll
  for (int w = 0; w < 4; w++)
    if (w < (tid >> 6)) wbase += wsum[w];
  int ex = wbase + incl - s;
  int exs[4] = {ex, ex + d0, ex + d0 + d1, ex + d0 + d1 + d2};
  int ds[4] = {d0, d1, d2, d3};
#pragma unroll
  for (int k = 0; k < 4; k++) {
    int node = node0 + tid * 4 + k;
    if (node < NN) {
      unsigned int st = (unsigned int)(cbase + exs[k]);
      rp32[g * NN + node] = st | ((unsigned int)ds[k] << 20);
      float di = rsqrtf((float)ds[k] + 1.0f);   // deg incl. self loop
      dinv[g * NN + node] = di;
      dinvh[g * NN + node] = h16(di);
    }
  }
}

// fillp: scatter packed (src | fp16 dinv[src]) into bucket-local colp slots.
// Writes stay within this bucket's 64KB window -> full line utilization.
__global__ __launch_bounds__(256) void fillp_kernel(const unsigned int* __restrict__ binned,
    const int* __restrict__ gcur, const unsigned int* __restrict__ rp32,
    const unsigned short* __restrict__ dinvh, unsigned int* __restrict__ colp) {
  __shared__ int cur[BW];
  int g = blockIdx.y, b = blockIdx.x;
  int tid = threadIdx.x;
  int node0 = b * BW;
  int cbase = b * CAP;
  int total = min(gcur[g * NBUCK + b] - cbase, CAP);
  const unsigned int* bp = binned + (size_t)g * REGION + cbase;
  for (int i = tid; i < BW; i += 256) {
    int node = node0 + i;
    cur[i] = (node < NN) ? (int)(rp32[g * NN + node] & 0xFFFFFu) : 0;
  }
  __syncthreads();
  const unsigned short* dh = dinvh + (size_t)g * NN;
  unsigned int* cg = colp + (size_t)g * REGION;
  for (int e = tid; e < total; e += 256) {
    unsigned int p = bp[e];
    int srcid = (int)(p & 0xffffu);
    int r = atomicAdd(&cur[(int)(p >> 16) - node0], 1);
    cg[r] = (unsigned int)srcid | ((unsigned int)dh[srcid] << 16);
  }
}

#define ALD 136   // padded LDS row stride (halves); 272B, 16B-aligned, conflict-light

// ---------------- R16: fused layer-1 (aggregation + 3-branch MFMA) ----------------
// 512 threads / 8 waves / 128-row tile. Per branch b: stage Ws(b) || aggregate the
// 128 rows straight into LDS As (4 iters x 8 waves x 4 node-groups, proven R14
// inner loop), sync, 8-wave MFMA (64x32 tile per wave) + bias + relu + max-merge.
// Deletes t1 entirely (37.5MB write + 38.4MB read + mmf1's staging).
// Rationale: aggb proved THROUGHPUT-bound, not occupancy-bound (R15), so the
// gather phase survives 2 blocks/CU; co-resident block's MFMA overlaps gathers.
__global__ __launch_bounds__(512, 4) void flayer_kernel(
    const __half* __restrict__ srch, const unsigned int* __restrict__ rp32,
    const unsigned int* __restrict__ colp, const float* __restrict__ dinv,
    const __half* __restrict__ Wf,
    const float* __restrict__ B0, const float* __restrict__ B1, const float* __restrict__ B2,
    __half* __restrict__ outh, int M) {
  __shared__ _Float16 As[128 * ALD];  // 34.8 KB
  __shared__ _Float16 Ws[16384];      // 32 KB
  const float* Bb[3] = {B0, B1, B2};
  const int tid = threadIdx.x;
  const int wave = tid >> 6, lane = tid & 63;
  const int grp = lane >> 4;          // node-group (agg) == quad (mfma)
  const int l16 = lane & 15;          // feature slot (agg) == ln (mfma)
  const int gb = grp << 4;
  const int wr = (wave >> 2) * 64, wc = (wave & 3) * 32;
  const int row0 = blockIdx.x * 128;
  const _Float16* srcv = (const _Float16*)srch;
  float om[4][2][4];

  for (int b = 0; b < 3; b++) {
    const __half* Wb = Wf + (size_t)b * 16384;
#pragma unroll
    for (int i = 0; i < 4; i++) {
      int id = tid + i * 512;
      *(half8*)&Ws[id * 8] = *(const half8*)&Wb[(size_t)id * 8];
    }
    // ---- aggregation phase: rows 0..127 of this tile, branch b ----
    const unsigned int* cp = colp + (size_t)b * REGION;
    for (int it = 0; it < 4; it++) {
      int r = it * 32 + wave * 4 + grp;
      int w = row0 + r;
      int node = (w < M) ? w : (M - 1);          // tail rows: recompute row M-1
      unsigned int r32 = rp32[(size_t)b * NN + node];
      int s = (int)(r32 & 0xFFFFFu);
      int n = (int)(r32 >> 20);
      float di = dinv[b * NN + node];
      half8 selfh = *(const half8*)&srcv[(size_t)node * D + l16 * 8];
      float a[8];
#pragma unroll
      for (int k = 0; k < 8; k++) a[k] = di * (float)selfh[k];
      int nmax = n;
      nmax = max(nmax, __shfl_xor(nmax, 16, 64));
      nmax = max(nmax, __shfl_xor(nmax, 32, 64));
      for (int j0 = 0; j0 < nmax; j0 += 16) {
        unsigned int c = (j0 + l16 < n) ? __builtin_nontemporal_load(&cp[s + j0 + l16]) : 0u;
        int rem = nmax - j0;
        rem = (rem > 16) ? 16 : rem;
        for (int jj = 0; jj < rem; jj += 4) {
          unsigned int v0 = (unsigned int)__shfl((int)c, gb + jj + 0, 64);
          unsigned int v1 = (unsigned int)__shfl((int)c, gb + jj + 1, 64);
          unsigned int v2 = (unsigned int)__shfl((int)c, gb + jj + 2, 64);
          unsigned int v3 = (unsigned int)__shfl((int)c, gb + jj + 3, 64);
          half8 h0 = *(const half8*)&srcv[(size_t)(v0 & 0xffffu) * D + l16 * 8];
          half8 h1 = *(const half8*)&srcv[(size_t)(v1 & 0xffffu) * D + l16 * 8];
          half8 h2 = *(const half8*)&srcv[(size_t)(v2 & 0xffffu) * D + l16 * 8];
          half8 h3 = *(const half8*)&srcv[(size_t)(v3 & 0xffffu) * D + l16 * 8];
          float w0 = wextract(v0), w1 = wextract(v1);
          float w2 = wextract(v2), w3 = wextract(v3);
#pragma unroll
          for (int k = 0; k < 8; k++) a[k] = fmaf((float)h0[k], w0, a[k]);
#pragma unroll
          for (int k = 0; k < 8; k++) a[k] = fmaf((float)h1[k], w1, a[k]);
#pragma unroll
          for (int k = 0; k < 8; k++) a[k] = fmaf((float)h2[k], w2, a[k]);
#pragma unroll
          for (int k = 0; k < 8; k++) a[k] = fmaf((float)h3[k], w3, a[k]);
        }
      }
      half8 o;
#pragma unroll
      for (int k = 0; k < 8; k++) o[k] = (_Float16)(di * a[k]);
      *(half8*)&As[r * ALD + l16 * 8] = o;       // fp16, same precision as old t1
    }
    __syncthreads();

    // ---- MFMA phase: 8 waves, each 64 rows x 32 cols ----
    float bias[2];
#pragma unroll
    for (int ct = 0; ct < 2; ct++) bias[ct] = Bb[b][wc + ct * 16 + l16];
    floatx4 acc[4][2];
#pragma unroll
    for (int rt = 0; rt < 4; rt++)
#pragma unroll
      for (int ct = 0; ct < 2; ct++)
        acc[rt][ct] = (floatx4){bias[ct], bias[ct], bias[ct], bias[ct]};
#pragma unroll
    for (int ks = 0; ks < 4; ks++) {
      half8 av[4];
#pragma unroll
      for (int rt = 0; rt < 4; rt++)
        av[rt] = *(const half8*)&As[(wr + rt * 16 + l16) * ALD + ks * 32 + grp * 8];
#pragma unroll
      for (int ct = 0; ct < 2; ct++) {
        int tt = (wc >> 4) + ct;
        half8 bv = *(const half8*)&Ws[((tt * 4 + ks) * 64 + lane) * 8];
#pragma unroll
        for (int rt = 0; rt < 4; rt++)
          acc[rt][ct] = __builtin_amdgcn_mfma_f32_16x16x32_f16(av[rt], bv, acc[rt][ct], 0, 0, 0);
      }
    }
#pragma unroll
    for (int rt = 0; rt < 4; rt++)
#pragma unroll
      for (int ct = 0; ct < 2; ct++)
#pragma unroll
        for (int r = 0; r < 4; r++) {
          float v = fmaxf(acc[rt][ct][r], 0.f);
          om[rt][ct][r] = (b == 0) ? v : fmaxf(om[rt][ct][r], v);
        }
    __syncthreads();   // before next branch overwrites As/Ws
  }
  // ---- epilogue: fp16 store ----
#pragma unroll
  for (int rt = 0; rt < 4; rt++) {
    int m = row0 + wr + rt * 16 + grp * 4;
#pragma unroll
    for (int r = 0; r < 4; r++) {
      if (m + r < M) {
#pragma unroll
        for (int ct = 0; ct < 2; ct++) {
          int n = wc + ct * 16 + l16;
          outh[(size_t)(m + r) * D + n] = __float2half(om[rt][ct][r]);
        }
      }
    }
  }
}

// ---------------- aggregation (layer 2 only): one wave per 4 (node, branch) rows ----
// Proven R14 form (batch-4, plain loads/stores). blockIdx.y = branch.
__global__ __launch_bounds__(256) void aggb_kernel(
    const __half* __restrict__ srch, const unsigned int* __restrict__ rp32,
    const unsigned int* __restrict__ colp, const float* __restrict__ dinv,
    const int* __restrict__ index, __half* __restrict__ tout, int nrows) {
  int b = blockIdx.y;
  int lane = threadIdx.x & 63;
  int grp = lane >> 4;
  int l16 = lane & 15;
  int gb = grp << 4;
  int wv = (blockIdx.x * 256 + threadIdx.x) >> 6;
  int w = wv * 4 + grp;
  int valid = (w < nrows);
  int wc = valid ? w : 0;
  int node = index ? index[wc] : wc;
  const _Float16* srcv = (const _Float16*)srch;
  unsigned int r32 = rp32[(size_t)b * NN + node];
  int s = (int)(r32 & 0xFFFFFu);
  int n = valid ? (int)(r32 >> 20) : 0;
  float di = dinv[b * NN + node];
  half8 selfh = *(const half8*)&srcv[(size_t)node * D + l16 * 8];
  float a[8];
#pragma unroll
  for (int k = 0; k < 8; k++) a[k] = di * (float)selfh[k];
  int nmax = n;
  nmax = max(nmax, __shfl_xor(nmax, 16, 64));
  nmax = max(nmax, __shfl_xor(nmax, 32, 64));
  const unsigned int* cp = colp + (size_t)b * REGION;
  for (int j0 = 0; j0 < nmax; j0 += 16) {
    unsigned int c = (j0 + l16 < n) ? cp[s + j0 + l16] : 0u;
    int rem = nmax - j0;
    rem = (rem > 16) ? 16 : rem;
    for (int jj = 0; jj < rem; jj += 4) {
      unsigned int v0 = (unsigned int)__shfl((int)c, gb + jj + 0, 64);
      unsigned int v1 = (unsigned int)__shfl((int)c, gb + jj + 1, 64);
      unsigned int v2 = (unsigned int)__shfl((int)c, gb + jj + 2, 64);
      unsigned int v3 = (unsigned int)__shfl((int)c, gb + jj + 3, 64);
      half8 h0 = *(const half8*)&srcv[(size_t)(v0 & 0xffffu) * D + l16 * 8];
      half8 h1 = *(const half8*)&srcv[(size_t)(v1 & 0xffffu) * D + l16 * 8];
      half8 h2 = *(const half8*)&srcv[(size_t)(v2 & 0xffffu) * D + l16 * 8];
      half8 h3 = *(const half8*)&srcv[(size_t)(v3 & 0xffffu) * D + l16 * 8];
      float w0 = wextract(v0), w1 = wextract(v1);
      float w2 = wextract(v2), w3 = wextract(v3);
#pragma unroll
      for (int k = 0; k < 8; k++) a[k] = fmaf((float)h0[k], w0, a[k]);
#pragma unroll
      for (int k = 0; k < 8; k++) a[k] = fmaf((float)h1[k], w1, a[k]);
#pragma unroll
      for (int k = 0; k < 8; k++) a[k] = fmaf((float)h2[k], w2, a[k]);
#pragma unroll
      for (int k = 0; k < 8; k++) a[k] = fmaf((float)h3[k], w3, a[k]);
    }
  }
  if (valid) {
    half8 o;
#pragma unroll
    for (int k = 0; k < 8; k++) o[k] = (_Float16)(di * a[k]);
    _Float16* tv = (_Float16*)tout;
    *(half8*)&tv[(size_t)b * nrows * D + (size_t)w * D + l16 * 8] = o;
  }
}

// ---------------- 3-branch MFMA matmul + bias + relu + max (layer 2 only) ----------

__global__ __launch_bounds__(256) void mmf_kernel(const __half* __restrict__ A,
    const __half* __restrict__ Wf,
    const float* __restrict__ B0, const float* __restrict__ B1, const float* __restrict__ B2,
    __half* __restrict__ outh, float* __restrict__ outf, int M) {
  __shared__ _Float16 As[128 * ALD];  // 34.8 KB
  __shared__ _Float16 Ws[16384];      // 32 KB
  const float* Bb[3] = {B0, B1, B2};
  const int tid = threadIdx.x;
  const int wave = tid >> 6, lane = tid & 63;
  const int wr = (wave >> 1) * 64, wc = (wave & 1) * 64;
  const int ln = lane & 15, quad = lane >> 4;
  const int row0 = blockIdx.x * 128;
  float om[4][4][4];

  for (int b = 0; b < 3; b++) {
    const __half* Wb = Wf + (size_t)b * 16384;
#pragma unroll
    for (int i = 0; i < 8; i++) {
      int id = tid + i * 256;
      *(half8*)&Ws[id * 8] = *(const half8*)&Wb[(size_t)id * 8];
    }
    const __half* Ab = A + (size_t)b * M * D;
#pragma unroll
    for (int i = 0; i < 8; i++) {
      int idx = tid + i * 256;          // 0..2047 half8 slots
      int r = idx >> 4, c8 = idx & 15;
      int gr = row0 + r;
      gr = (gr < M) ? gr : (M - 1);
      half8 v = *(const half8*)&Ab[(size_t)gr * D + c8 * 8];
      *(half8*)&As[r * ALD + c8 * 8] = v;
    }
    __syncthreads();

    float bias[4];
#pragma unroll
    for (int ct = 0; ct < 4; ct++) bias[ct] = Bb[b][wc + ct * 16 + ln];
    floatx4 acc[4][4];
#pragma unroll
    for (int rt = 0; rt < 4; rt++)
#pragma unroll
      for (int ct = 0; ct < 4; ct++)
        acc[rt][ct] = (floatx4){bias[ct], bias[ct], bias[ct], bias[ct]};

#pragma unroll
    for (int ks = 0; ks < 4; ks++) {
      half8 av[4];
#pragma unroll
      for (int rt = 0; rt < 4; rt++)
        av[rt] = *(const half8*)&As[(wr + rt * 16 + ln) * ALD + ks * 32 + quad * 8];
#pragma unroll
      for (int ct = 0; ct < 4; ct++) {
        int tt = (wc >> 4) + ct;
        half8 bv = *(const half8*)&Ws[((tt * 4 + ks) * 64 + lane) * 8];
#pragma unroll
        for (int rt = 0; rt < 4; rt++)
          acc[rt][ct] = __builtin_amdgcn_mfma_f32_16x16x32_f16(av[rt], bv, acc[rt][ct], 0, 0, 0);
      }
    }
#pragma unroll
    for (int rt = 0; rt < 4; rt++)
#pragma unroll
      for (int ct = 0; ct < 4; ct++)
#pragma unroll
        for (int r = 0; r < 4; r++) {
          float v = fmaxf(acc[rt][ct][r], 0.f);
          om[rt][ct][r] = (b == 0) ? v : fmaxf(om[rt][ct][r], v);
        }
    __syncthreads();
  }
#pragma unroll
  for (int rt = 0; rt < 4; rt++) {
    int m = row0 + wr + rt * 16 + quad * 4;
#pragma unroll
    for (int r = 0; r < 4; r++) {
      if (m + r < M) {
#pragma unroll
        for (int ct = 0; ct < 4; ct++) {
          int n = wc + ct * 16 + ln;
          if (outh) outh[(size_t)(m + r) * D + n] = __float2half(om[rt][ct][r]);
          else      outf[(size_t)(m + r) * D + n] = om[rt][ct][r];
        }
      }
    }
  }
}

// ---------------- launch ----------------

extern "C" void kernel_launch(void* const* d_in, const int* in_sizes, int n_in,
                              void* d_out, int out_size, void* d_ws, size_t ws_size,
                              hipStream_t stream) {
  const float* x = (const float*)d_in[0];
  const int* e0 = (const int*)d_in[1];
  const int* e1 = (const int*)d_in[2];
  const int* e2 = (const int*)d_in[3];
  const int* index = (const int*)d_in[4];
  const float* w1[3] = {(const float*)d_in[5], (const float*)d_in[9],  (const float*)d_in[13]};
  const float* b1[3] = {(const float*)d_in[6], (const float*)d_in[10], (const float*)d_in[14]};
  const float* w2[3] = {(const float*)d_in[7], (const float*)d_in[11], (const float*)d_in[15]};
  const float* b2[3] = {(const float*)d_in[8], (const float*)d_in[12], (const float*)d_in[16]};
  float* out = (float*)d_out;

  char* ws = (char*)d_ws;
  size_t o = 0;
  auto alloc = [&](size_t bytes) {
    o = (o + 255) & ~(size_t)255;
    void* p = ws + o;
    o += bytes;
    return p;
  };
  unsigned int* rp32 = (unsigned int*)alloc((size_t)NG * NN * 4);
  unsigned int* colp = (unsigned int*)alloc((size_t)NG * REGION * 4);   // 9.6 MB
  float*  dinv   = (float*)alloc((size_t)NG * NN * 4);
  unsigned short* dinvh = (unsigned short*)alloc((size_t)NG * NN * 2);
  int*    gcur   = (int*)alloc((size_t)NG * NBUCK * 4);
  __half* xh     = (__half*)alloc((size_t)NN * D * 2);        // 12.8 MB
  __half* Wf     = (__half*)alloc((size_t)6 * 128 * 128 * 2); // 196 KB
  // scratch: binned (9.6 MB) during prep chain, then t2 (3 MB) during layer 2
  unsigned int* binned = (unsigned int*)alloc((size_t)NG * REGION * 4);
  __half* hacc   = (__half*)alloc((size_t)NN * D * 2);        // 12.8 MB
  __half* t2     = (__half*)binned;   // alias: binned dead after fillp
  (void)ws_size; (void)in_sizes; (void)n_in; (void)out_size;

  prep_kernel<<<XCVT_BLKS + WCVT_BLKS + 1, 256, 0, stream>>>(
      x, xh, w1[0], w1[1], w1[2], w2[0], w2[1], w2[2], Wf, gcur);
  bin_kernel<<<dim3(NBLK_BIN, NG), 256, 0, stream>>>(e0, e1, e2, gcur, binned);
  csr_kernel<<<dim3(NBUCK, NG), 256, 0, stream>>>(binned, gcur, rp32, dinv, dinvh);
  fillp_kernel<<<dim3(NBUCK, NG), 256, 0, stream>>>(binned, gcur, rp32, dinvh, colp);

  // layer 1 (fused): hacc = max_b relu(Norm_b(xh) @ W1_b + b1_b)   [fp16]
  flayer_kernel<<<(NN + 127) / 128, 512, 0, stream>>>(
      xh, rp32, colp, dinv, Wf, b1[0], b1[1], b1[2], hacc, NN);
  // layer 2: t2_b = Norm_b(hacc)[index];  out = max_b relu(t2_b @ W2_b + b2_b)
  aggb_kernel<<<dim3((NI + 15) / 16, NG), 256, 0, stream>>>(
      hacc, rp32, colp, dinv, index, t2, NI);
  mmf_kernel<<<(NI + 127) / 128, 256, 0, stream>>>(t2, Wf + (size_t)3 * 16384,
                                                   b2[0], b2[1], b2[2], nullptr, out, NI);
}